// Round 3
// baseline (387.851 us; speedup 1.0000x reference)
//
#include <hip/hip_runtime.h>
#include <math.h>

#define NB   4
#define SEQ  2048
#define DM   512
#define KS   16
#define ROWS (NB*SEQ)   // 8192

// ---------------------------------------------------------------------------
// Kernel 1: deltas = softplus(toks @ W_delta^T + b_delta); dx = deltas * toks
// 64x64 output tile, BK=32, 256 threads, 4x4 micro-tile per thread. f32.
// ---------------------------------------------------------------------------
#define BM 64
#define BN 64
#define BK 32
#define LDP 68   // padded LDS stride (68*4B = 272B, 16B-aligned rows)

__device__ __forceinline__ float softplus_f(float z) {
    return z > 20.f ? z : log1pf(__expf(z));
}

__global__ __launch_bounds__(256)
void k_delta(const float* __restrict__ toks, const float* __restrict__ Wd,
             const float* __restrict__ bd, float* __restrict__ odelta,
             float* __restrict__ odx)
{
    __shared__ float As[BK][LDP];
    __shared__ float Ws[BK][LDP];
    const int tid = threadIdx.x;
    const int rowBase = blockIdx.x * BM;
    const int colBase = blockIdx.y * BN;
    const int tr = tid >> 4;          // 0..15
    const int tc = tid & 15;          // 0..15
    const int lm = tid >> 2;          // 0..63 : tile row (or W row) loaded
    const int le = (tid & 3) << 3;    // 0,8,16,24 : e-offset loaded

    float acc[4][4] = {};

    const float* gA = toks + (size_t)(rowBase + lm) * DM + le;
    const float* gW = Wd   + (size_t)(colBase + lm) * DM + le;

    for (int e0 = 0; e0 < DM; e0 += BK) {
        float4 a0 = *(const float4*)(gA);
        float4 a1 = *(const float4*)(gA + 4);
        float4 w0 = *(const float4*)(gW);
        float4 w1 = *(const float4*)(gW + 4);
        gA += BK; gW += BK;

        __syncthreads();   // previous iteration done reading LDS
        As[le+0][lm] = a0.x; As[le+1][lm] = a0.y; As[le+2][lm] = a0.z; As[le+3][lm] = a0.w;
        As[le+4][lm] = a1.x; As[le+5][lm] = a1.y; As[le+6][lm] = a1.z; As[le+7][lm] = a1.w;
        Ws[le+0][lm] = w0.x; Ws[le+1][lm] = w0.y; Ws[le+2][lm] = w0.z; Ws[le+3][lm] = w0.w;
        Ws[le+4][lm] = w1.x; Ws[le+5][lm] = w1.y; Ws[le+6][lm] = w1.z; Ws[le+7][lm] = w1.w;
        __syncthreads();

        #pragma unroll
        for (int e = 0; e < BK; ++e) {
            float4 av = *(const float4*)&As[e][tr << 2];
            float4 wv = *(const float4*)&Ws[e][tc << 2];
            float a_[4] = {av.x, av.y, av.z, av.w};
            float w_[4] = {wv.x, wv.y, wv.z, wv.w};
            #pragma unroll
            for (int i = 0; i < 4; ++i)
                #pragma unroll
                for (int j = 0; j < 4; ++j)
                    acc[i][j] = fmaf(a_[i], w_[j], acc[i][j]);
        }
    }

    // epilogue: + bias, softplus, dx = delta * x
    const int d0 = colBase + (tc << 2);
    const float4 bv = *(const float4*)(bd + d0);
    #pragma unroll
    for (int i = 0; i < 4; ++i) {
        const int r = rowBase + (tr << 2) + i;
        const float4 tv = *(const float4*)(toks + (size_t)r * DM + d0);
        float4 dl, dxv;
        dl.x = softplus_f(acc[i][0] + bv.x);
        dl.y = softplus_f(acc[i][1] + bv.y);
        dl.z = softplus_f(acc[i][2] + bv.z);
        dl.w = softplus_f(acc[i][3] + bv.w);
        dxv.x = dl.x * tv.x; dxv.y = dl.y * tv.y;
        dxv.z = dl.z * tv.z; dxv.w = dl.w * tv.w;
        *(float4*)(odelta + (size_t)r * DM + d0) = dl;
        *(float4*)(odx    + (size_t)r * DM + d0) = dxv;
    }
}

// ---------------------------------------------------------------------------
// Kernel 2: Bs = toks @ W_B^T, Cs = toks @ W_C^T   ([ROWS,16] each)
// 16 rows per block; thread (k, row_local); broadcast toks loads, L1-hot W.
// ---------------------------------------------------------------------------
__global__ __launch_bounds__(256)
void k_bc(const float* __restrict__ toks, const float* __restrict__ WB,
          const float* __restrict__ WC, float* __restrict__ oB,
          float* __restrict__ oC)
{
    const int tid = threadIdx.x;
    const int k  = tid & 15;
    const int rl = tid >> 4;                 // 0..15
    const int row = blockIdx.x * 16 + rl;
    const float* tp = toks + (size_t)row * DM;
    const float* wb = WB + (size_t)k * DM;
    const float* wc = WC + (size_t)k * DM;
    float ab = 0.f, ac = 0.f;
    #pragma unroll 4
    for (int e = 0; e < DM; e += 4) {
        float4 tv = *(const float4*)(tp + e);
        float4 bv = *(const float4*)(wb + e);
        float4 cv = *(const float4*)(wc + e);
        ab = fmaf(tv.x, bv.x, ab); ab = fmaf(tv.y, bv.y, ab);
        ab = fmaf(tv.z, bv.z, ab); ab = fmaf(tv.w, bv.w, ab);
        ac = fmaf(tv.x, cv.x, ac); ac = fmaf(tv.y, cv.y, ac);
        ac = fmaf(tv.z, cv.z, ac); ac = fmaf(tv.w, cv.w, ac);
    }
    oB[(size_t)row * KS + k] = ab;
    oC[(size_t)row * KS + k] = ac;
}

// ---------------------------------------------------------------------------
// Kernel 3: bidirectional selective scan + time-sum reduction.
// Thread = (k, d, n, dir). h <- exp(delta*Ac)*h + dx*B ; acc += h*C.
// Reduce over k (16 lanes), atomicAdd into out (pre-zeroed).
// ---------------------------------------------------------------------------
__global__ __launch_bounds__(256)
void k_scan(const float* __restrict__ de, const float* __restrict__ dx,
            const float* __restrict__ Bs, const float* __restrict__ Cs,
            const float* __restrict__ logA, float* __restrict__ out)
{
    const int g   = blockIdx.x * blockDim.x + threadIdx.x;
    const int k   = g & 15;
    const int d   = (g >> 4) & (DM - 1);
    const int n   = (g >> 13) & (NB - 1);
    const int dir = (g >> 15) & 1;

    const float Ac = -__expf(logA[d * KS + k]);

    const int t0  = dir ? (SEQ - 1) : 0;
    const int sgn = dir ? -1 : 1;
    const size_t rbase = ((size_t)n * SEQ + t0);

    const float* pd = de + rbase * DM + d;
    const float* px = dx + rbase * DM + d;
    const float* pb = Bs + rbase * KS + k;
    const float* pc = Cs + rbase * KS + k;
    const int sD = sgn * DM;
    const int sK = sgn * KS;

    float h = 0.f, acc = 0.f;
    #pragma unroll 4
    for (int t = 0; t < SEQ; ++t) {
        const float dev = *pd;
        const float bxv = *px;
        const float bv  = *pb;
        const float cv  = *pc;
        pd += sD; px += sD; pb += sK; pc += sK;
        const float a = __expf(dev * Ac);
        h   = fmaf(a, h, bxv * bv);
        acc = fmaf(h, cv, acc);
    }

    // reduce over k (low 4 lane bits)
    acc += __shfl_xor(acc, 1);
    acc += __shfl_xor(acc, 2);
    acc += __shfl_xor(acc, 4);
    acc += __shfl_xor(acc, 8);

    if (k == 0)
        atomicAdd(&out[n * DM + d], acc * (1.0f / SEQ));
}

// ---------------------------------------------------------------------------
extern "C" void kernel_launch(void* const* d_in, const int* in_sizes, int n_in,
                              void* d_out, int out_size, void* d_ws, size_t ws_size,
                              hipStream_t stream) {
    const float* toks = (const float*)d_in[0];
    const float* logA = (const float*)d_in[1];
    const float* WB   = (const float*)d_in[2];
    const float* WC   = (const float*)d_in[3];
    const float* Wd   = (const float*)d_in[4];
    const float* bd   = (const float*)d_in[5];
    float* out = (float*)d_out;

    float* ws    = (float*)d_ws;
    float* wdel  = ws;                                   // ROWS*DM
    float* wdx   = wdel + (size_t)ROWS * DM;             // ROWS*DM
    float* wB    = wdx  + (size_t)ROWS * DM;             // ROWS*KS
    float* wC    = wB   + (size_t)ROWS * KS;             // ROWS*KS

    hipMemsetAsync(d_out, 0, sizeof(float) * NB * DM, stream);

    k_delta<<<dim3(ROWS / BM, DM / BN), 256, 0, stream>>>(toks, Wd, bd, wdel, wdx);
    k_bc<<<ROWS / 16, 256, 0, stream>>>(toks, WB, WC, wB, wC);
    k_scan<<<(NB * DM * KS * 2) / 256, 256, 0, stream>>>(wdel, wdx, wB, wC, logA, out);
}

// Round 5
// 278.047 us; speedup vs baseline: 1.3949x; 1.3949x over previous
//
#include <hip/hip_runtime.h>
#include <math.h>

#define NB   4
#define SEQ  2048
#define DM   512
#define KS   16
#define ROWS (NB*SEQ)   // 8192

#define NCHUNK 16
#define CLEN   (SEQ / NCHUNK)          // 128
#define CH_TOT (2 * NB * NCHUNK * DM * KS)   // 1,048,576 per array

// ---------------------------------------------------------------------------
// Kernel 1: deltas = softplus(toks @ W_delta^T + b_delta); dx = deltas * toks
// 64x64 output tile, BK=32, 256 threads, 4x4 micro-tile per thread. f32.
// ---------------------------------------------------------------------------
#define BM 64
#define BN 64
#define BK 32
#define LDP 68   // padded LDS stride

__device__ __forceinline__ float softplus_f(float z) {
    return z > 20.f ? z : log1pf(__expf(z));
}

__global__ __launch_bounds__(256)
void k_delta(const float* __restrict__ toks, const float* __restrict__ Wd,
             const float* __restrict__ bd, float* __restrict__ odelta,
             float* __restrict__ odx)
{
    __shared__ float As[BK][LDP];
    __shared__ float Ws[BK][LDP];
    const int tid = threadIdx.x;
    const int rowBase = blockIdx.x * BM;
    const int colBase = blockIdx.y * BN;
    const int tr = tid >> 4;          // 0..15
    const int tc = tid & 15;          // 0..15
    const int lm = tid >> 2;          // 0..63
    const int le = (tid & 3) << 3;    // 0,8,16,24

    float acc[4][4] = {};

    const float* gA = toks + (size_t)(rowBase + lm) * DM + le;
    const float* gW = Wd   + (size_t)(colBase + lm) * DM + le;

    for (int e0 = 0; e0 < DM; e0 += BK) {
        float4 a0 = *(const float4*)(gA);
        float4 a1 = *(const float4*)(gA + 4);
        float4 w0 = *(const float4*)(gW);
        float4 w1 = *(const float4*)(gW + 4);
        gA += BK; gW += BK;

        __syncthreads();
        As[le+0][lm] = a0.x; As[le+1][lm] = a0.y; As[le+2][lm] = a0.z; As[le+3][lm] = a0.w;
        As[le+4][lm] = a1.x; As[le+5][lm] = a1.y; As[le+6][lm] = a1.z; As[le+7][lm] = a1.w;
        Ws[le+0][lm] = w0.x; Ws[le+1][lm] = w0.y; Ws[le+2][lm] = w0.z; Ws[le+3][lm] = w0.w;
        Ws[le+4][lm] = w1.x; Ws[le+5][lm] = w1.y; Ws[le+6][lm] = w1.z; Ws[le+7][lm] = w1.w;
        __syncthreads();

        #pragma unroll
        for (int e = 0; e < BK; ++e) {
            float4 av = *(const float4*)&As[e][tr << 2];
            float4 wv = *(const float4*)&Ws[e][tc << 2];
            float a_[4] = {av.x, av.y, av.z, av.w};
            float w_[4] = {wv.x, wv.y, wv.z, wv.w};
            #pragma unroll
            for (int i = 0; i < 4; ++i)
                #pragma unroll
                for (int j = 0; j < 4; ++j)
                    acc[i][j] = fmaf(a_[i], w_[j], acc[i][j]);
        }
    }

    const int d0 = colBase + (tc << 2);
    const float4 bv = *(const float4*)(bd + d0);
    #pragma unroll
    for (int i = 0; i < 4; ++i) {
        const int r = rowBase + (tr << 2) + i;
        const float4 tv = *(const float4*)(toks + (size_t)r * DM + d0);
        float4 dl, dxv;
        dl.x = softplus_f(acc[i][0] + bv.x);
        dl.y = softplus_f(acc[i][1] + bv.y);
        dl.z = softplus_f(acc[i][2] + bv.z);
        dl.w = softplus_f(acc[i][3] + bv.w);
        dxv.x = dl.x * tv.x; dxv.y = dl.y * tv.y;
        dxv.z = dl.z * tv.z; dxv.w = dl.w * tv.w;
        *(float4*)(odelta + (size_t)r * DM + d0) = dl;
        *(float4*)(odx    + (size_t)r * DM + d0) = dxv;
    }
}

// ---------------------------------------------------------------------------
// Kernel 2: Bs = toks @ W_B^T, Cs = toks @ W_C^T   ([ROWS,16] each)
// ---------------------------------------------------------------------------
__global__ __launch_bounds__(256)
void k_bc(const float* __restrict__ toks, const float* __restrict__ WB,
          const float* __restrict__ WC, float* __restrict__ oB,
          float* __restrict__ oC)
{
    const int tid = threadIdx.x;
    const int k  = tid & 15;
    const int rl = tid >> 4;
    const int row = blockIdx.x * 16 + rl;
    const float* tp = toks + (size_t)row * DM;
    const float* wb = WB + (size_t)k * DM;
    const float* wc = WC + (size_t)k * DM;
    float ab = 0.f, ac = 0.f;
    #pragma unroll 4
    for (int e = 0; e < DM; e += 4) {
        float4 tv = *(const float4*)(tp + e);
        float4 bv = *(const float4*)(wb + e);
        float4 cv = *(const float4*)(wc + e);
        ab = fmaf(tv.x, bv.x, ab); ab = fmaf(tv.y, bv.y, ab);
        ab = fmaf(tv.z, bv.z, ab); ab = fmaf(tv.w, bv.w, ab);
        ac = fmaf(tv.x, cv.x, ac); ac = fmaf(tv.y, cv.y, ac);
        ac = fmaf(tv.z, cv.z, ac); ac = fmaf(tv.w, cv.w, ac);
    }
    oB[(size_t)row * KS + k] = ab;
    oC[(size_t)row * KS + k] = ac;
}

// ---------------------------------------------------------------------------
// Kernel 3a: chunked scan, pass 1. Thread = (dir,n,chunk,d,k).
// Computes chunk summary: h_end = P*h0 + Q ; sum_t c_t h_t = R*h0 + S.
//   per step: a = exp(de*Ac); u = a*u + dx*B; A *= a; R += c*A; S += c*u
// ---------------------------------------------------------------------------
__global__ __launch_bounds__(256)
void k_scan_chunk(const float* __restrict__ de, const float* __restrict__ dx,
                  const float* __restrict__ Bs, const float* __restrict__ Cs,
                  const float* __restrict__ logA,
                  float* __restrict__ oP, float* __restrict__ oQ,
                  float* __restrict__ oR, float* __restrict__ oS)
{
    const int g     = blockIdx.x * blockDim.x + threadIdx.x;
    const int k     = g & 15;
    const int d     = (g >> 4) & (DM - 1);
    const int chunk = (g >> 13) & (NCHUNK - 1);
    const int n     = (g >> 17) & (NB - 1);
    const int dir   = (g >> 19) & 1;

    const float Ac = -__expf(logA[d * KS + k]);

    const int sgn = dir ? -1 : 1;
    const int t0  = dir ? (SEQ - 1 - chunk * CLEN) : (chunk * CLEN);
    const size_t rbase = (size_t)n * SEQ + t0;

    const float* pd = de + rbase * DM + d;
    const float* px = dx + rbase * DM + d;
    const float* pb = Bs + rbase * KS + k;
    const float* pc = Cs + rbase * KS + k;
    const int sD = sgn * DM;
    const int sK = sgn * KS;

    float A = 1.f, u = 0.f, R = 0.f, S = 0.f;
    #pragma unroll 4
    for (int t = 0; t < CLEN; ++t) {
        const float dev = *pd;
        const float bxv = *px;
        const float bv  = *pb;
        const float cv  = *pc;
        pd += sD; px += sD; pb += sK; pc += sK;
        const float a = __expf(dev * Ac);
        u = fmaf(a, u, bxv * bv);
        A = A * a;
        R = fmaf(cv, A, R);
        S = fmaf(cv, u, S);
    }

    const size_t idx = ((((size_t)dir * NB + n) * NCHUNK + chunk) * DM + d) * KS + k;
    oP[idx] = A; oQ[idx] = u; oR[idx] = R; oS[idx] = S;
}

// ---------------------------------------------------------------------------
// Kernel 3b: compose chunk summaries in scan order; k-reduce; atomicAdd.
// Thread = (dir,n,d,k); 16 chunks serial.
// ---------------------------------------------------------------------------
__global__ __launch_bounds__(256)
void k_scan_fix(const float* __restrict__ oP, const float* __restrict__ oQ,
                const float* __restrict__ oR, const float* __restrict__ oS,
                float* __restrict__ out)
{
    const int g   = blockIdx.x * blockDim.x + threadIdx.x;
    const int k   = g & 15;
    const int d   = (g >> 4) & (DM - 1);
    const int n   = (g >> 13) & (NB - 1);
    const int dir = (g >> 15) & 1;

    size_t idx = ((((size_t)dir * NB + n) * NCHUNK) * DM + d) * KS + k;
    const size_t stride = (size_t)DM * KS;

    float h = 0.f, acc = 0.f;
    #pragma unroll
    for (int c = 0; c < NCHUNK; ++c) {
        const float P = oP[idx];
        const float Q = oQ[idx];
        const float R = oR[idx];
        const float S = oS[idx];
        idx += stride;
        acc = fmaf(R, h, acc) + S;
        h   = fmaf(P, h, Q);
    }

    acc += __shfl_xor(acc, 1);
    acc += __shfl_xor(acc, 2);
    acc += __shfl_xor(acc, 4);
    acc += __shfl_xor(acc, 8);

    if (k == 0)
        atomicAdd(&out[n * DM + d], acc * (1.0f / SEQ));
}

// ---------------------------------------------------------------------------
extern "C" void kernel_launch(void* const* d_in, const int* in_sizes, int n_in,
                              void* d_out, int out_size, void* d_ws, size_t ws_size,
                              hipStream_t stream) {
    const float* toks = (const float*)d_in[0];
    const float* logA = (const float*)d_in[1];
    const float* WB   = (const float*)d_in[2];
    const float* WC   = (const float*)d_in[3];
    const float* Wd   = (const float*)d_in[4];
    const float* bd   = (const float*)d_in[5];
    float* out = (float*)d_out;

    float* ws    = (float*)d_ws;
    float* wdel  = ws;                                   // ROWS*DM      = 4.19M
    float* wdx   = wdel + (size_t)ROWS * DM;             // ROWS*DM      = 4.19M
    float* wB    = wdx  + (size_t)ROWS * DM;             // ROWS*KS
    float* wC    = wB   + (size_t)ROWS * KS;             // ROWS*KS
    float* wP    = wC   + (size_t)ROWS * KS;             // CH_TOT = 1M each
    float* wQ    = wP   + (size_t)CH_TOT;
    float* wR    = wQ   + (size_t)CH_TOT;
    float* wS    = wR   + (size_t)CH_TOT;

    hipMemsetAsync(d_out, 0, sizeof(float) * NB * DM, stream);

    k_delta<<<dim3(ROWS / BM, DM / BN), 256, 0, stream>>>(toks, Wd, bd, wdel, wdx);
    k_bc<<<ROWS / 16, 256, 0, stream>>>(toks, WB, WC, wB, wC);
    k_scan_chunk<<<(2 * NB * NCHUNK * DM * KS) / 256, 256, 0, stream>>>(
        wdel, wdx, wB, wC, logA, wP, wQ, wR, wS);
    k_scan_fix<<<(2 * NB * DM * KS) / 256, 256, 0, stream>>>(wP, wQ, wR, wS, out);
}

// Round 8
// 233.160 us; speedup vs baseline: 1.6635x; 1.1925x over previous
//
#include <hip/hip_runtime.h>
#include <math.h>

#define NB   4
#define SEQ  2048
#define DM   512
#define KS   16
#define ROWS (NB*SEQ)   // 8192

#define NCHUNK 16
#define CLEN   (SEQ / NCHUNK)          // 128
#define CH_TOT (2 * NB * NCHUNK * DM * KS)   // 1,048,576 per array

// ---------------------------------------------------------------------------
// Kernel 1 (fused): deltas = softplus(toks@Wd^T + bd); dx = deltas*toks;
//                   Bs = toks@WB^T; Cs = toks@WC^T   (grid.y == 8 tile)
// 128x64 tile, BK=16, 256 threads, 8x4 micro-tile, reg-prefetched staging.
// ---------------------------------------------------------------------------
#define BM 128
#define BN 64
#define BK 16
#define LDA (BM + 4)   // 132: bank((g*4+i)*4 + row) -> 2-way max (free)
#define LDB (BN + 4)   // 68

__device__ __forceinline__ float softplus_f(float z) {
    return z > 20.f ? z : log1pf(__expf(z));
}

__global__ __launch_bounds__(256)
void k_delta_fused(const float* __restrict__ toks, const float* __restrict__ Wd,
                   const float* __restrict__ WB,   const float* __restrict__ WC,
                   const float* __restrict__ bd,
                   float* __restrict__ odelta, float* __restrict__ odx,
                   float* __restrict__ oB,     float* __restrict__ oC)
{
    __shared__ float As[BK][LDA];
    __shared__ float Bs[BK][LDB];
    const int tid = threadIdx.x;
    const int rowBase = blockIdx.x * BM;
    const int by   = blockIdx.y;            // 0..8
    const bool isBC = (by == 8);
    const int colBase = by * BN;

    // compute mapping: 16x16 threads, each 8 rows x 4 cols
    const int tm = tid >> 4;                // 0..15 -> rows tm*8..+7
    const int tn = tid & 15;                // 0..15 -> cols tn*4..+3

    // loader mapping: 4 consecutive lanes cover one row's 4 float4 groups
    const int lrow = tid >> 2;              // 0..63
    const int lgrp = tid & 3;               // 0..3 -> float offset lgrp*4

    const float* gA0 = toks + (size_t)(rowBase + lrow) * DM + lgrp * 4;
    const float* gA1 = gA0 + (size_t)64 * DM;

    bool bvalid;
    const float* gB;
    if (!isBC) {
        bvalid = true;
        gB = Wd + (size_t)(colBase + lrow) * DM + lgrp * 4;
    } else {
        bvalid = (lrow < 32);
        const float* base = (lrow < 16) ? (WB + (size_t)lrow * DM)
                                        : (WC + (size_t)(lrow - 16) * DM);
        gB = base + lgrp * 4;
    }

    float acc[8][4] = {};

    // prefetch tile 0 into registers
    float4 pa0 = *(const float4*)(gA0);
    float4 pa1 = *(const float4*)(gA1);
    float4 pb  = make_float4(0.f, 0.f, 0.f, 0.f);
    if (bvalid) pb = *(const float4*)(gB);

    for (int e0 = 0; e0 < DM; e0 += BK) {
        __syncthreads();   // previous inner loop done reading LDS
        As[lgrp*4+0][lrow]    = pa0.x; As[lgrp*4+1][lrow]    = pa0.y;
        As[lgrp*4+2][lrow]    = pa0.z; As[lgrp*4+3][lrow]    = pa0.w;
        As[lgrp*4+0][lrow+64] = pa1.x; As[lgrp*4+1][lrow+64] = pa1.y;
        As[lgrp*4+2][lrow+64] = pa1.z; As[lgrp*4+3][lrow+64] = pa1.w;
        Bs[lgrp*4+0][lrow]    = pb.x;  Bs[lgrp*4+1][lrow]    = pb.y;
        Bs[lgrp*4+2][lrow]    = pb.z;  Bs[lgrp*4+3][lrow]    = pb.w;
        __syncthreads();

        // prefetch next tile (latency hides under the 512-FMA inner loop)
        if (e0 + BK < DM) {
            pa0 = *(const float4*)(gA0 + e0 + BK);
            pa1 = *(const float4*)(gA1 + e0 + BK);
            if (bvalid) pb = *(const float4*)(gB + e0 + BK);
        }

        #pragma unroll
        for (int e = 0; e < BK; ++e) {
            const float4 a0 = *(const float4*)&As[e][tm * 8];
            const float4 a1 = *(const float4*)&As[e][tm * 8 + 4];
            const float4 bf = *(const float4*)&Bs[e][tn * 4];
            const float av[8] = {a0.x, a0.y, a0.z, a0.w, a1.x, a1.y, a1.z, a1.w};
            const float bv[4] = {bf.x, bf.y, bf.z, bf.w};
            #pragma unroll
            for (int i = 0; i < 8; ++i)
                #pragma unroll
                for (int j = 0; j < 4; ++j)
                    acc[i][j] = fmaf(av[i], bv[j], acc[i][j]);
        }
    }

    if (!isBC) {
        const int c0 = colBase + tn * 4;
        const float4 bv = *(const float4*)(bd + c0);
        #pragma unroll
        for (int i = 0; i < 8; ++i) {
            const int r = rowBase + tm * 8 + i;
            const float4 tv = *(const float4*)(toks + (size_t)r * DM + c0);
            float4 dl, dxv;
            dl.x = softplus_f(acc[i][0] + bv.x);
            dl.y = softplus_f(acc[i][1] + bv.y);
            dl.z = softplus_f(acc[i][2] + bv.z);
            dl.w = softplus_f(acc[i][3] + bv.w);
            dxv.x = dl.x * tv.x; dxv.y = dl.y * tv.y;
            dxv.z = dl.z * tv.z; dxv.w = dl.w * tv.w;
            *(float4*)(odelta + (size_t)r * DM + c0) = dl;
            *(float4*)(odx    + (size_t)r * DM + c0) = dxv;
        }
    } else if (tn < 8) {
        float* dst = (tn < 4) ? (oB + tn * 4) : (oC + (tn - 4) * 4);
        #pragma unroll
        for (int i = 0; i < 8; ++i) {
            const int r = rowBase + tm * 8 + i;
            *(float4*)(dst + (size_t)r * KS) =
                make_float4(acc[i][0], acc[i][1], acc[i][2], acc[i][3]);
        }
    }
}

// ---------------------------------------------------------------------------
// Kernel 3a: chunked scan, pass 1. Thread = (dir,n,chunk,d,k).
// Chunk summary: h_end = P*h0 + Q ; sum_t c_t h_t = R*h0 + S.
// ---------------------------------------------------------------------------
__global__ __launch_bounds__(256)
void k_scan_chunk(const float* __restrict__ de, const float* __restrict__ dx,
                  const float* __restrict__ Bsp, const float* __restrict__ Csp,
                  const float* __restrict__ logA,
                  float* __restrict__ oP, float* __restrict__ oQ,
                  float* __restrict__ oR, float* __restrict__ oS)
{
    const int g     = blockIdx.x * blockDim.x + threadIdx.x;
    const int k     = g & 15;
    const int d     = (g >> 4) & (DM - 1);
    const int chunk = (g >> 13) & (NCHUNK - 1);
    const int n     = (g >> 17) & (NB - 1);
    const int dir   = (g >> 19) & 1;

    const float Ac = -__expf(logA[d * KS + k]);

    const int sgn = dir ? -1 : 1;
    const int t0  = dir ? (SEQ - 1 - chunk * CLEN) : (chunk * CLEN);
    const size_t rbase = (size_t)n * SEQ + t0;

    const float* pd = de  + rbase * DM + d;
    const float* px = dx  + rbase * DM + d;
    const float* pb = Bsp + rbase * KS + k;
    const float* pc = Csp + rbase * KS + k;
    const int sD = sgn * DM;
    const int sK = sgn * KS;

    float A = 1.f, u = 0.f, R = 0.f, S = 0.f;
    #pragma unroll 4
    for (int t = 0; t < CLEN; ++t) {
        const float dev = *pd;
        const float bxv = *px;
        const float bv  = *pb;
        const float cv  = *pc;
        pd += sD; px += sD; pb += sK; pc += sK;
        const float a = __expf(dev * Ac);
        u = fmaf(a, u, bxv * bv);
        A = A * a;
        R = fmaf(cv, A, R);
        S = fmaf(cv, u, S);
    }

    const size_t idx = ((((size_t)dir * NB + n) * NCHUNK + chunk) * DM + d) * KS + k;
    oP[idx] = A; oQ[idx] = u; oR[idx] = R; oS[idx] = S;
}

// ---------------------------------------------------------------------------
// Kernel 3b: compose chunk summaries in scan order; k-reduce; atomicAdd.
// ---------------------------------------------------------------------------
__global__ __launch_bounds__(256)
void k_scan_fix(const float* __restrict__ oP, const float* __restrict__ oQ,
                const float* __restrict__ oR, const float* __restrict__ oS,
                float* __restrict__ out)
{
    const int g   = blockIdx.x * blockDim.x + threadIdx.x;
    const int k   = g & 15;
    const int d   = (g >> 4) & (DM - 1);
    const int n   = (g >> 13) & (NB - 1);
    const int dir = (g >> 15) & 1;

    size_t idx = ((((size_t)dir * NB + n) * NCHUNK) * DM + d) * KS + k;
    const size_t stride = (size_t)DM * KS;

    float h = 0.f, acc = 0.f;
    #pragma unroll
    for (int c = 0; c < NCHUNK; ++c) {
        const float P = oP[idx];
        const float Q = oQ[idx];
        const float R = oR[idx];
        const float S = oS[idx];
        idx += stride;
        acc = fmaf(R, h, acc) + S;
        h   = fmaf(P, h, Q);
    }

    acc += __shfl_xor(acc, 1);
    acc += __shfl_xor(acc, 2);
    acc += __shfl_xor(acc, 4);
    acc += __shfl_xor(acc, 8);

    if (k == 0)
        atomicAdd(&out[n * DM + d], acc * (1.0f / SEQ));
}

// ---------------------------------------------------------------------------
extern "C" void kernel_launch(void* const* d_in, const int* in_sizes, int n_in,
                              void* d_out, int out_size, void* d_ws, size_t ws_size,
                              hipStream_t stream) {
    const float* toks = (const float*)d_in[0];
    const float* logA = (const float*)d_in[1];
    const float* WB   = (const float*)d_in[2];
    const float* WC   = (const float*)d_in[3];
    const float* Wd   = (const float*)d_in[4];
    const float* bd   = (const float*)d_in[5];
    float* out = (float*)d_out;

    float* ws    = (float*)d_ws;
    float* wdel  = ws;                                   // ROWS*DM
    float* wdx   = wdel + (size_t)ROWS * DM;             // ROWS*DM
    float* wB    = wdx  + (size_t)ROWS * DM;             // ROWS*KS
    float* wC    = wB   + (size_t)ROWS * KS;             // ROWS*KS
    float* wP    = wC   + (size_t)ROWS * KS;             // CH_TOT each
    float* wQ    = wP   + (size_t)CH_TOT;
    float* wR    = wQ   + (size_t)CH_TOT;
    float* wS    = wR   + (size_t)CH_TOT;

    hipMemsetAsync(d_out, 0, sizeof(float) * NB * DM, stream);

    k_delta_fused<<<dim3(ROWS / BM, 9), 256, 0, stream>>>(
        toks, Wd, WB, WC, bd, wdel, wdx, wB, wC);
    k_scan_chunk<<<(2 * NB * NCHUNK * DM * KS) / 256, 256, 0, stream>>>(
        wdel, wdx, wB, wC, logA, wP, wQ, wR, wS);
    k_scan_fix<<<(2 * NB * DM * KS) / 256, 256, 0, stream>>>(wP, wQ, wR, wS, out);
}